// Round 5
// baseline (324.404 us; speedup 1.0000x reference)
//
#include <hip/hip_runtime.h>
#include <hip/hip_bf16.h>
#include <math.h>

// Problem constants: N=100000, K=10, T=7, D=7, O=32
#define T_ 7
#define D_ 7
#define K_ 10
#define O_ 32
#define NPB 64            // nodes per block == 1 wave: no inter-wave barriers
#define NREP 16           // replicated global accumulators (atomic spread)
#define NEG_SLOPE 0.01f

// async global->LDS DMA, 16B per lane. LDS dest: wave-uniform base, HW adds lane*16.
__device__ __forceinline__ void gl_lds16(const float4* g, float4* lds_wave_base) {
    __builtin_amdgcn_global_load_lds(
        (const __attribute__((address_space(1))) void*)g,
        (__attribute__((address_space(3))) void*)lds_wave_base,
        16, 0, 0);
}

// ---------------- K0: zero the replicated output accumulators --------------
__global__ void k0_zero(float* __restrict__ acc) {
    int i = threadIdx.x;
    if (i < NREP * O_) acc[i] = 0.f;
}

// ---------------- fused kernel (single-wave blocks) ------------------------
// One block = one wave = 64 nodes. Per t: issue all 18 tile chunks via async
// global_load_lds, waitcnt, compute from LDS. h[56] in registers. W_content
// and W_agg are uniform-indexed -> scalar loads (SGPR/scalar-cache), no LDS.
// Epilogue: [56]x[O,56]^T, sigmoid, wave butterfly reduce, 32-lane atomic.
__global__ __launch_bounds__(NPB) void k_fused(
    const float* __restrict__ xhet,   // [T,N,K,D]
    const float* __restrict__ xnode,  // [N,D]
    const int*   __restrict__ types,  // [N]
    const float* __restrict__ Wc,     // [T,D,D]
    const float* __restrict__ bc,     // [T,D]
    const float* __restrict__ Wagg,   // [O,56]
    const float* __restrict__ bagg,   // [O]
    float* __restrict__ acc_out,      // [NREP][O] global accumulators
    int N)
{
    __shared__ __align__(16) float tile[NPB * 70];   // 17920 B -> ~9 blocks/CU

    const int lane = threadIdx.x;     // 0..63
    const int nodeBase = blockIdx.x * NPB;
    const int n = nodeBase + lane;
    const bool active = (n < N);
    const int valid = min(NPB, N - nodeBase);
    const int L  = valid * 70;        // floats in this block's tile
    const int L4 = L >> 2;            // full float4 count (1120 when full)

    // per-thread self inputs (tiny, cache-resident)
    float x[D_]; int tp = -1;
    if (active) {
        tp = types[n];
        #pragma unroll
        for (int d = 0; d < D_; ++d) x[d] = xnode[(size_t)n * D_ + d];
    } else {
        #pragma unroll
        for (int d = 0; d < D_; ++d) x[d] = 0.f;
    }

    float h[(T_ + 1) * D_];           // concat layout: h[t*7+o], self at 49..55
    #pragma unroll
    for (int j = 0; j < (T_ + 1) * D_; ++j) h[j] = 0.f;

    float4* tile4 = (float4*)tile;

    for (int t = 0; t < T_; ++t) {
        // block-uniform weights -> scalar regs
        float w[D_][D_], bias[D_];
        #pragma unroll
        for (int o = 0; o < D_; ++o) {
            bias[o] = bc[t * D_ + o];
            #pragma unroll
            for (int d = 0; d < D_; ++d) w[o][d] = Wc[(t * D_ + o) * D_ + d];
        }

        const float*  src  = xhet + ((size_t)t * N + nodeBase) * 70;
        const float4* src4 = (const float4*)src;     // 16B-aligned

        __syncthreads();  // 1-wave block: compiles to waitcnt only (prev readers done)

        // ---- issue ALL chunks async global->LDS (up to 18 in flight)
        #pragma unroll
        for (int j = 0; j < 18; ++j) {               // ceil(1120/64)=18 when full
            const int i = j * NPB + lane;
            if (i < L4) gl_lds16(src4 + i, tile4 + j * NPB);
        }
        // generic tail (only if L%4 != 0; impossible for even `valid`)
        for (int i = (L4 << 2) + lane; i < L; i += NPB) tile[i] = src[i];

        __syncthreads();  // drains vmcnt -> async LDS writes visible

        if (active) {
            const float* myp = tile + lane * 70;
            float acc[D_] = {0.f, 0.f, 0.f, 0.f, 0.f, 0.f, 0.f};
            float cnt = 0.f;
            #pragma unroll
            for (int kk = 0; kk < K_ / 2; ++kk) {    // k in pairs: 14 floats = 7 float2
                float f[14];
                const float2* p2 = (const float2*)(myp + kk * 14);
                #pragma unroll
                for (int j = 0; j < 7; ++j) { float2 v = p2[j]; f[2*j] = v.x; f[2*j+1] = v.y; }
                #pragma unroll
                for (int hh = 0; hh < 2; ++hh) {
                    float pre[D_];
                    #pragma unroll
                    for (int o = 0; o < D_; ++o) pre[o] = bias[o];
                    #pragma unroll
                    for (int d = 0; d < D_; ++d) {
                        const float xv = f[hh * 7 + d];
                        #pragma unroll
                        for (int o = 0; o < D_; ++o) pre[o] = fmaf(xv, w[o][d], pre[o]);
                    }
                    bool nz = false;
                    #pragma unroll
                    for (int o = 0; o < D_; ++o) nz = nz || (pre[o] != 0.f);
                    cnt += nz ? 1.f : 0.f;
                    #pragma unroll
                    for (int o = 0; o < D_; ++o)
                        acc[o] += (pre[o] >= 0.f) ? pre[o] : NEG_SLOPE * pre[o];
                }
            }
            const float inv = 1.f / fmaxf(cnt, 1.f);
            #pragma unroll
            for (int o = 0; o < D_; ++o) h[t * D_ + o] = acc[o] * inv;

            // self candidate with this t's uniform weights; select on type match
            float ps[D_];
            #pragma unroll
            for (int o = 0; o < D_; ++o) {
                float p = bias[o];
                #pragma unroll
                for (int d = 0; d < D_; ++d) p = fmaf(x[d], w[o][d], p);
                ps[o] = (p >= 0.f) ? p : NEG_SLOPE * p;
            }
            if (tp == t) {
                #pragma unroll
                for (int o = 0; o < D_; ++o) h[T_ * D_ + o] = ps[o];
            }
        }
    }

    // ---- epilogue: [56] x [O,56]^T + bias -> sigmoid -> butterfly reduce
    float keep = 0.f;
    #pragma unroll 4
    for (int o = 0; o < O_; ++o) {
        float s = bagg[o];                             // uniform -> scalar load
        const float4* wrow = (const float4*)(Wagg + o * 56);  // 224B stride, 16B-aligned
        #pragma unroll
        for (int q = 0; q < 14; ++q) {
            float4 wv4 = wrow[q];                      // uniform -> s_load_dwordx4
            s += h[4*q] * wv4.x + h[4*q+1] * wv4.y + h[4*q+2] * wv4.z + h[4*q+3] * wv4.w;
        }
        float val = active ? 1.f / (1.f + __expf(-s)) : 0.f;
        #pragma unroll
        for (int m = 1; m < 64; m <<= 1) val += __shfl_xor(val, m);  // all lanes get sum
        if (lane == o) keep = val;
    }
    const int rep = blockIdx.x & (NREP - 1);
    if (lane < O_) atomicAdd(acc_out + rep * O_ + lane, keep);
}

// ---------------- K3: sum replicas, divide by N into d_out -----------------
__global__ void k3_finish(const float* __restrict__ acc, float* __restrict__ out, float invN) {
    int o = threadIdx.x;
    if (o < O_) {
        float s = 0.f;
        #pragma unroll
        for (int rr = 0; rr < NREP; ++rr) s += acc[rr * O_ + o];
        out[o] = s * invN;
    }
}

extern "C" void kernel_launch(void* const* d_in, const int* in_sizes, int n_in,
                              void* d_out, int out_size, void* d_ws, size_t ws_size,
                              hipStream_t stream) {
    const float* xnode = (const float*)d_in[0];   // [N,D]
    const float* xhet  = (const float*)d_in[1];   // [T,N,K,D]
    const int*   types = (const int*)d_in[2];     // [N]
    const float* Wc    = (const float*)d_in[3];   // [T,D,D]
    const float* bc    = (const float*)d_in[4];   // [T,D]
    const float* Wagg  = (const float*)d_in[5];   // [O,56]
    const float* bagg  = (const float*)d_in[6];   // [O]
    float* out = (float*)d_out;

    const int N = in_sizes[2];
    float* acc_out = (float*)d_ws;                // NREP*32 floats

    const int nblk = (N + NPB - 1) / NPB;

    k0_zero<<<1, 512, 0, stream>>>(acc_out);
    k_fused<<<nblk, NPB, 0, stream>>>(xhet, xnode, types, Wc, bc, Wagg, bagg, acc_out, N);
    k3_finish<<<1, 64, 0, stream>>>(acc_out, out, 1.f / (float)N);
}